// Round 1
// baseline (296.622 us; speedup 1.0000x reference)
//
#include <hip/hip_runtime.h>

#define NC    80
#define B_    16
#define NA    3
#define H_    80
#define W_    80
#define D_    85
#define NLAB  48
#define NCELL (B_*NA*H_*W_)   // 307200

__device__ __forceinline__ float softplusf(float x) {
    // JAX softplus = logaddexp(x, 0) = max(x,0) + log1p(exp(-|x|))
    return fmaxf(x, 0.f) + log1pf(expf(-fabsf(x)));
}

// ---------------------------------------------------------------------------
// Kernel 1: target assignment. One thread per (b, n) label. Later n wins at a
// cell (scan overwrite order) -> atomicMax with n on winner grid init'd to -1.
// ---------------------------------------------------------------------------
__global__ void assign_k(const float* __restrict__ lxywh,
                         int* __restrict__ win) {
    int t = blockIdx.x * blockDim.x + threadIdx.x;
    if (t >= B_ * NLAB) return;
    int b = t / NLAB, n = t % NLAB;

    const float* L = lxywh + (size_t)(b * NLAB + n) * 4;
    float gx = L[0] * 640.f, gy = L[1] * 640.f;
    float gw = L[2] * 640.f, gh = L[3] * 640.f;

    float fx = fminf(fmaxf(gx * 0.125f, 0.f), 79.999f);
    float fy = fminf(fmaxf(gy * 0.125f, 0.f), 79.999f);
    int gi = (int)fx, gj = (int)fy;

    // best anchor by IoU-of-WH in grid units; argmax keeps first on tie
    float gtw = gw * 0.125f, gth = gh * 0.125f;
    const float aw[3] = {1.25f, 2.0f, 4.125f};
    const float ah[3] = {1.625f, 3.75f, 2.875f};
    int a = 0; float best = -1.f;
    #pragma unroll
    for (int k = 0; k < 3; k++) {
        float inter = fminf(gtw, aw[k]) * fminf(gth, ah[k]);
        float uni   = gtw * gth + aw[k] * ah[k] - inter + 1e-9f;
        float r = inter / uni;
        if (r > best) { best = r; a = k; }
    }

    #pragma unroll
    for (int di = -1; di <= 1; di++) {
        #pragma unroll
        for (int dj = -1; dj <= 1; dj++) {
            int ii = min(max(gi + di, 0), W_ - 1);
            int jj = min(max(gj + dj, 0), H_ - 1);
            int cell = ((b * NA + a) * H_ + jj) * W_ + ii;
            atomicMax(&win[cell], n);
        }
    }
}

// ---------------------------------------------------------------------------
// Kernel 2: main loss. One thread per cell. Reads only channel 4 everywhere;
// positive cells (~2%) additionally read their 85-float cell + winner label.
// Wave-reduce 4 partial sums, one atomicAdd per wave per sum.
// ---------------------------------------------------------------------------
__global__ void main_k(const float* __restrict__ p,
                       const float* __restrict__ lxywh,
                       const int*   __restrict__ lcls,
                       const int*   __restrict__ win,
                       float* __restrict__ acc) {
    int idx = blockIdx.x * blockDim.x + threadIdx.x;
    float obj = 0.f, box = 0.f, cls = 0.f, npos = 0.f;

    if (idx < NCELL) {
        int n = win[idx];
        const float* pc = p + (size_t)idx * D_;
        float xo = pc[4];
        float t = (n >= 0) ? 1.f : 0.f;
        obj = softplusf(xo) - t * xo;

        if (n >= 0) {
            npos = 1.f;
            int b = idx / (NA * H_ * W_);
            int a = (idx / (H_ * W_)) % NA;
            int j = (idx / W_) % H_;
            int i = idx % W_;

            const float AW[3] = {10.f, 16.f, 33.f};
            const float AH[3] = {13.f, 30.f, 23.f};

            float p0 = pc[0], p1 = pc[1], p2 = pc[2], p3 = pc[3];
            float sx = 1.f / (1.f + expf(-p0));
            float sy = 1.f / (1.f + expf(-p1));
            float px = ((float)i + sx) * 8.f;
            float py = ((float)j + sy) * 8.f;
            float pw = expf(p2) * AW[a];
            float ph = expf(p3) * AH[a];

            const float* L = lxywh + (size_t)(b * NLAB + n) * 4;
            float gx = L[0] * 640.f, gy = L[1] * 640.f;
            float gw = L[2] * 640.f, gh = L[3] * 640.f;

            // CIoU (forward value; alpha is stop-gradient so just a value here)
            float px1 = px - pw * 0.5f, px2 = px + pw * 0.5f;
            float py1 = py - ph * 0.5f, py2 = py + ph * 0.5f;
            float gx1 = gx - gw * 0.5f, gx2 = gx + gw * 0.5f;
            float gy1 = gy - gh * 0.5f, gy2 = gy + gh * 0.5f;

            float iw = fmaxf(fminf(px2, gx2) - fmaxf(px1, gx1), 0.f);
            float ih = fmaxf(fminf(py2, gy2) - fmaxf(py1, gy1), 0.f);
            float inter = iw * ih;
            float ap = fmaxf(px2 - px1, 0.f) * fmaxf(py2 - py1, 0.f);
            float ag = fmaxf(gx2 - gx1, 0.f) * fmaxf(gy2 - gy1, 0.f);
            float uni = ap + ag - inter + 1e-7f;
            float iou = inter / uni;

            float cw = fmaxf(fmaxf(px2, gx2) - fminf(px1, gx1), 0.f);
            float ch = fmaxf(fmaxf(py2, gy2) - fminf(py1, gy1), 0.f);
            float c2 = cw * cw + ch * ch + 1e-7f;
            float rho2 = (px - gx) * (px - gx) + (py - gy) * (py - gy);

            float dv = atanf(gw / (gh + 1e-7f)) - atanf(pw / (ph + 1e-7f));
            float v = 0.40528473456935108577f * dv * dv;   // 4/pi^2
            float alpha = v / (1.f - iou + v + 1e-7f);
            box = 1.f - (iou - rho2 / c2 - alpha * v);

            int c = lcls[b * NLAB + n];
            float cs = 0.f;
            for (int d = 0; d < NC; d++) {
                float x = pc[5 + d];
                cs += softplusf(x) - ((d == c) ? x : 0.f);
            }
            cls = cs;
        }
    }

    // wave64 butterfly reduce
    #pragma unroll
    for (int o = 32; o; o >>= 1) {
        obj  += __shfl_xor(obj,  o);
        box  += __shfl_xor(box,  o);
        cls  += __shfl_xor(cls,  o);
        npos += __shfl_xor(npos, o);
    }
    if ((threadIdx.x & 63) == 0) {
        atomicAdd(&acc[0], obj);
        atomicAdd(&acc[1], box);
        atomicAdd(&acc[2], cls);
        atomicAdd(&acc[3], npos);
    }
}

// ---------------------------------------------------------------------------
// Kernel 3: finalize scalar.
// ---------------------------------------------------------------------------
__global__ void final_k(const float* __restrict__ acc, float* __restrict__ out) {
    float npos = fmaxf(acc[3], 1.f);
    float total = 7.5f * acc[1] / npos
                + acc[0] / (float)NCELL
                + 0.5f * acc[2] / (npos * (float)NC);
    out[0] = total;
}

extern "C" void kernel_launch(void* const* d_in, const int* in_sizes, int n_in,
                              void* d_out, int out_size, void* d_ws, size_t ws_size,
                              hipStream_t stream) {
    const float* p    = (const float*)d_in[0];
    const float* lx   = (const float*)d_in[1];
    const int*   lc   = (const int*)d_in[2];
    float*       out  = (float*)d_out;

    int*   win = (int*)d_ws;
    float* acc = (float*)((char*)d_ws + (size_t)NCELL * sizeof(int));

    hipMemsetAsync(win, 0xFF, (size_t)NCELL * sizeof(int), stream);  // -1
    hipMemsetAsync(acc, 0, 4 * sizeof(float), stream);

    assign_k<<<(B_ * NLAB + 255) / 256, 256, 0, stream>>>(lx, win);
    main_k<<<(NCELL + 255) / 256, 256, 0, stream>>>(p, lx, lc, win, acc);
    final_k<<<1, 1, 0, stream>>>(acc, out);
}

// Round 2
// 48.035 us; speedup vs baseline: 6.1751x; 6.1751x over previous
//
#include <hip/hip_runtime.h>

#define NC    80
#define B_    16
#define NA    3
#define H_    80
#define W_    80
#define D_    85
#define NLAB  48
#define NCELL (B_*NA*H_*W_)   // 307200
#define NBLK  (NCELL/256)     // 1200 blocks for obj_k
#define MAXPOS (B_*NLAB*9)    // 6912 upper bound on positive cells

__device__ __forceinline__ float softplusf(float x) {
    // JAX softplus = max(x,0) + log1p(exp(-|x|))
    return fmaxf(x, 0.f) + log1pf(expf(-fabsf(x)));
}

// ---------------------------------------------------------------------------
// Kernel 1: target assignment. One thread per (b,n) label. Later n wins at a
// cell (scan overwrite order) -> atomicMax(win[cell], n), win init'd to -1.
// ---------------------------------------------------------------------------
__global__ void assign_k(const float* __restrict__ lxywh,
                         int* __restrict__ win) {
    int t = blockIdx.x * blockDim.x + threadIdx.x;
    if (t >= B_ * NLAB) return;
    int b = t / NLAB, n = t % NLAB;

    const float* L = lxywh + (size_t)(b * NLAB + n) * 4;
    float gx = L[0] * 640.f, gy = L[1] * 640.f;
    float gw = L[2] * 640.f, gh = L[3] * 640.f;

    float fx = fminf(fmaxf(gx * 0.125f, 0.f), 79.999f);
    float fy = fminf(fmaxf(gy * 0.125f, 0.f), 79.999f);
    int gi = (int)fx, gj = (int)fy;

    float gtw = gw * 0.125f, gth = gh * 0.125f;
    const float aw[3] = {1.25f, 2.0f, 4.125f};
    const float ah[3] = {1.625f, 3.75f, 2.875f};
    int a = 0; float best = -1.f;
    #pragma unroll
    for (int k = 0; k < 3; k++) {
        float inter = fminf(gtw, aw[k]) * fminf(gth, ah[k]);
        float uni   = gtw * gth + aw[k] * ah[k] - inter + 1e-9f;
        float r = inter / uni;
        if (r > best) { best = r; a = k; }
    }

    #pragma unroll
    for (int di = -1; di <= 1; di++) {
        #pragma unroll
        for (int dj = -1; dj <= 1; dj++) {
            int ii = min(max(gi + di, 0), W_ - 1);
            int jj = min(max(gj + dj, 0), H_ - 1);
            int cell = ((b * NA + a) * H_ + jj) * W_ + ii;
            atomicMax(&win[cell], n);
        }
    }
}

// ---------------------------------------------------------------------------
// Kernel 2: obj BCE over all cells + compaction of positive cells.
// Per-block LDS reduce -> obj_part[block] (no float atomics).
// One int atomicAdd per block for the positive-list base.
// ---------------------------------------------------------------------------
__global__ void obj_k(const float* __restrict__ p,
                      const int*   __restrict__ win,
                      float* __restrict__ obj_part,
                      int*   __restrict__ poslist,
                      int*   __restrict__ poscount) {
    int idx  = blockIdx.x * 256 + threadIdx.x;     // NCELL % 256 == 0
    int lane = threadIdx.x & 63;
    int wid  = threadIdx.x >> 6;

    int   n  = win[idx];
    float xo = p[(size_t)idx * D_ + 4];
    bool  pos = (n >= 0);
    float obj = softplusf(xo) - (pos ? xo : 0.f);

    unsigned long long m = __ballot(pos);
    int c64 = __popcll(m);

    __shared__ int   wpre[4];
    __shared__ int   wbase;
    __shared__ float wsum[4];

    // wave-reduce obj
    #pragma unroll
    for (int o = 32; o; o >>= 1) obj += __shfl_xor(obj, o);

    if (lane == 0) { wpre[wid] = c64; wsum[wid] = obj; }
    __syncthreads();
    if (threadIdx.x == 0) {
        int c0 = wpre[0], c1 = wpre[1], c2 = wpre[2], c3 = wpre[3];
        int tot = c0 + c1 + c2 + c3;
        wpre[0] = 0; wpre[1] = c0; wpre[2] = c0 + c1; wpre[3] = c0 + c1 + c2;
        wbase = tot ? atomicAdd(poscount, tot) : 0;
        obj_part[blockIdx.x] = wsum[0] + wsum[1] + wsum[2] + wsum[3];
    }
    __syncthreads();
    if (pos) {
        int off = __popcll(m & ((1ull << lane) - 1ull));
        poslist[wbase + wpre[wid] + off] = idx;
    }
}

// ---------------------------------------------------------------------------
// Kernel 3: one WAVE per positive cell. Lanes split the 80 class logits
// (coalesced contiguous loads); lane 0 computes CIoU. Per-wave partials,
// no atomics.
// ---------------------------------------------------------------------------
__global__ void pos_k(const float* __restrict__ p,
                      const float* __restrict__ lxywh,
                      const int*   __restrict__ lcls,
                      const int*   __restrict__ win,
                      const int*   __restrict__ poslist,
                      const int*   __restrict__ poscount,
                      float* __restrict__ box_part,
                      float* __restrict__ cls_part) {
    int gwave = (blockIdx.x * 256 + threadIdx.x) >> 6;
    int lane  = threadIdx.x & 63;
    int cnt   = *poscount;
    if (gwave >= cnt) return;

    int idx = poslist[gwave];
    int n   = win[idx];
    const float* pc = p + (size_t)idx * D_;

    int b = idx / (NA * H_ * W_);
    int c = lcls[b * NLAB + n];

    // class BCE: lane handles class `lane` and, for lane<16, class lane+64
    float cs;
    {
        float x = pc[5 + lane];
        cs = softplusf(x) - ((lane == c) ? x : 0.f);
    }
    if (lane < 16) {
        float x = pc[69 + lane];
        cs += softplusf(x) - ((lane + 64 == c) ? x : 0.f);
    }
    #pragma unroll
    for (int o = 32; o; o >>= 1) cs += __shfl_xor(cs, o);

    if (lane == 0) {
        int a = (idx / (H_ * W_)) % NA;
        int j = (idx / W_) % H_;
        int i = idx % W_;

        const float AW[3] = {10.f, 16.f, 33.f};
        const float AH[3] = {13.f, 30.f, 23.f};

        float p0 = pc[0], p1 = pc[1], p2 = pc[2], p3 = pc[3];
        float sx = 1.f / (1.f + expf(-p0));
        float sy = 1.f / (1.f + expf(-p1));
        float px = ((float)i + sx) * 8.f;
        float py = ((float)j + sy) * 8.f;
        float pw = expf(p2) * AW[a];
        float ph = expf(p3) * AH[a];

        const float* L = lxywh + (size_t)(b * NLAB + n) * 4;
        float gx = L[0] * 640.f, gy = L[1] * 640.f;
        float gw = L[2] * 640.f, gh = L[3] * 640.f;

        float px1 = px - pw * 0.5f, px2 = px + pw * 0.5f;
        float py1 = py - ph * 0.5f, py2 = py + ph * 0.5f;
        float gx1 = gx - gw * 0.5f, gx2 = gx + gw * 0.5f;
        float gy1 = gy - gh * 0.5f, gy2 = gy + gh * 0.5f;

        float iw = fmaxf(fminf(px2, gx2) - fmaxf(px1, gx1), 0.f);
        float ih = fmaxf(fminf(py2, gy2) - fmaxf(py1, gy1), 0.f);
        float inter = iw * ih;
        float ap = fmaxf(px2 - px1, 0.f) * fmaxf(py2 - py1, 0.f);
        float ag = fmaxf(gx2 - gx1, 0.f) * fmaxf(gy2 - gy1, 0.f);
        float uni = ap + ag - inter + 1e-7f;
        float iou = inter / uni;

        float cw = fmaxf(fmaxf(px2, gx2) - fminf(px1, gx1), 0.f);
        float ch = fmaxf(fmaxf(py2, gy2) - fminf(py1, gy1), 0.f);
        float c2 = cw * cw + ch * ch + 1e-7f;
        float rho2 = (px - gx) * (px - gx) + (py - gy) * (py - gy);

        float dv = atanf(gw / (gh + 1e-7f)) - atanf(pw / (ph + 1e-7f));
        float v = 0.40528473456935108577f * dv * dv;   // 4/pi^2
        float alpha = v / (1.f - iou + v + 1e-7f);
        float box = 1.f - (iou - rho2 / c2 - alpha * v);

        box_part[gwave] = box;
        cls_part[gwave] = cs;
    }
}

// ---------------------------------------------------------------------------
// Kernel 4: final reduce of partials + compose scalar.
// ---------------------------------------------------------------------------
__global__ void final_k(const float* __restrict__ obj_part,
                        const float* __restrict__ box_part,
                        const float* __restrict__ cls_part,
                        const int*   __restrict__ poscount,
                        float* __restrict__ out) {
    int cnt = *poscount;
    float o = 0.f, bx = 0.f, cl = 0.f;
    for (int t = threadIdx.x; t < NBLK; t += 256) o += obj_part[t];
    for (int t = threadIdx.x; t < cnt; t += 256) { bx += box_part[t]; cl += cls_part[t]; }
    #pragma unroll
    for (int s = 32; s; s >>= 1) {
        o  += __shfl_xor(o,  s);
        bx += __shfl_xor(bx, s);
        cl += __shfl_xor(cl, s);
    }
    __shared__ float so[4], sb[4], sc[4];
    int lane = threadIdx.x & 63, wid = threadIdx.x >> 6;
    if (lane == 0) { so[wid] = o; sb[wid] = bx; sc[wid] = cl; }
    __syncthreads();
    if (threadIdx.x == 0) {
        float O  = so[0] + so[1] + so[2] + so[3];
        float Bx = sb[0] + sb[1] + sb[2] + sb[3];
        float Cl = sc[0] + sc[1] + sc[2] + sc[3];
        float npos = fmaxf((float)cnt, 1.f);
        out[0] = 7.5f * Bx / npos + O / (float)NCELL + 0.5f * Cl / (npos * (float)NC);
    }
}

extern "C" void kernel_launch(void* const* d_in, const int* in_sizes, int n_in,
                              void* d_out, int out_size, void* d_ws, size_t ws_size,
                              hipStream_t stream) {
    const float* p  = (const float*)d_in[0];
    const float* lx = (const float*)d_in[1];
    const int*   lc = (const int*)d_in[2];
    float*       out = (float*)d_out;

    char* w = (char*)d_ws;
    int*   win      = (int*)w;                                  w += (size_t)NCELL * 4;
    int*   poscount = (int*)w;                                  w += 16;           // keep alignment
    float* obj_part = (float*)w;                                w += (size_t)NBLK * 4;
    float* box_part = (float*)w;                                w += (size_t)MAXPOS * 4;
    float* cls_part = (float*)w;                                w += (size_t)MAXPOS * 4;
    int*   poslist  = (int*)w;                                  w += (size_t)MAXPOS * 4;

    hipMemsetAsync(win, 0xFF, (size_t)NCELL * 4, stream);       // -1
    hipMemsetAsync(poscount, 0, 4, stream);

    assign_k<<<(B_ * NLAB + 255) / 256, 256, 0, stream>>>(lx, win);
    obj_k<<<NBLK, 256, 0, stream>>>(p, win, obj_part, poslist, poscount);
    pos_k<<<MAXPOS / 4, 256, 0, stream>>>(p, lx, lc, win, poslist, poscount,
                                          box_part, cls_part);
    final_k<<<1, 256, 0, stream>>>(obj_part, box_part, cls_part, poscount, out);
}